// Round 1
// baseline (402.579 us; speedup 1.0000x reference)
//
#include <hip/hip_runtime.h>

typedef float v4f __attribute__((ext_vector_type(4)));

namespace {
constexpr int B_     = 8;
constexpr int NT_    = 256;
constexpr int NX_    = 256;
constexpr int NREC_  = 64;
constexpr int PIECES = 8;              // vertical strips per batch
constexpr int IROWS  = 32;             // interior rows per strip
constexpr int G      = 16;             // ghost width = steps per round
constexpr int ROUNDS = NT_ / G;        // 16
constexpr float DT2  = 1e-6f;          // DT*DT
constexpr float KLAP = 1e-8f;          // DT*DT/(DH*DH)
constexpr size_t FLAGS_BYTES = 4096;
constexpr int RCAP = 6;
} // namespace

// lane i <- lane i-1 (shfl_up 1). Lane 0 gets 0.0f (bound_ctrl) -- masked by cf=0.
__device__ __forceinline__ float dpp_shr1(float v) {
    return __int_as_float(__builtin_amdgcn_update_dpp(
        0, __float_as_int(v), 0x138 /*WAVE_SHR1*/, 0xF, 0xF, true));
}
// lane i <- lane i+1 (shfl_down 1). Lane 63 gets 0.0f -- masked by cf=0.
__device__ __forceinline__ float dpp_shl1(float v) {
    return __int_as_float(__builtin_amdgcn_update_dpp(
        0, __float_as_int(v), 0x130 /*WAVE_SHL1*/, 0xF, 0xF, true));
}

// 64 blocks: piece p of batch b (blockIdx = p*8 + b). Each block evolves 64 ext
// rows (32 interior + 16 ghost each side); cross-block exchange every G=16
// steps via cached slabs + agent-scope flag handshake (R6-proven).
//
// R7: thread's own 4x4 tile of BOTH levels lives in REGISTERS; LDS holds only
// band-boundary halo rows -> ~4 b128 LDS ops/thread/step.
// R8 (this round): (a) east/west neighbors via DPP wave shifts instead of
// ds_bpermute -> DS pipe load halved, no lgkm chains in compute; (b) receiver
// samples staged in LDS recbuf and flushed once per round -> steady-state step
// has ZERO global ops, so the pre-barrier vmcnt(0) drain is free.
extern "C" __global__
__attribute__((amdgpu_flat_work_group_size(1024, 1024), amdgpu_waves_per_eu(4, 4)))
void wave_reg_kernel(const float* __restrict__ x,
                     const float* __restrict__ vp,
                     const int* __restrict__ src_loc,
                     const int* __restrict__ rec_loc,
                     float* __restrict__ out,
                     int* __restrict__ flags,   // [64] monotone round counters
                     float* __restrict__ gbuf)  // [par2][64][side2][lvl2][16][256]
{
    __shared__ float pub[2][2][16][256];   // 64 KB: [par][top/bot row][band][col]
    __shared__ float wav[NT_];             // 1 KB wavelet
    __shared__ float recbuf[G][NREC_];     // 4 KB receiver staging (per round)
    __shared__ unsigned char recown[NREC_];// per-rec ownership of this block

    const int bid  = blockIdx.x;
    const int b    = bid & 7;
    const int p    = bid >> 3;
    const int blk  = b * PIECES + p;
    const int tid  = threadIdx.x;
    const int band = tid >> 6;             // wave id 0..15 -> 4 ext rows
    const int lane = tid & 63;
    const int c0   = lane << 2;            // first owned col (0..252)
    const int grt  = p * IROWS - G + (band << 2);  // global row of owned row 0

    if (tid < NT_) wav[tid] = x[b * NT_ + tid];
    if (tid < NREC_) {
        int rz = rec_loc[(b * NREC_ + tid) * 2 + 0];
        recown[tid] = (rz >= p * IROWS && rz < p * IROWS + IROWS) ? 1 : 0;
    }

    // cf = vp^2*DT^2/DH^2, zeroed at Dirichlet boundary + out-of-domain rows
    v4f cf[4];
#pragma unroll
    for (int i = 0; i < 4; ++i) {
        int gr = grt + i;
        int crow = gr < 0 ? 0 : (gr > 255 ? 255 : gr);
        bool rowok = (gr >= 1) && (gr <= 254);
        v4f vv = *(const v4f*)&vp[crow * NX_ + c0];
        float cc[4];
#pragma unroll
        for (int k = 0; k < 4; ++k) {
            int col = c0 + k;
            float vk = (k == 0) ? vv.x : (k == 1) ? vv.y : (k == 2) ? vv.z : vv.w;
            cc[k] = (rowok && col >= 1 && col <= 254) ? vk * vk * KLAP : 0.f;
        }
        cf[i].x = cc[0]; cf[i].y = cc[1]; cf[i].z = cc[2]; cf[i].w = cc[3];
    }

    // source ownership (ghost rows included: ghost evolution must replay it)
    const int sz = src_loc[b * 2 + 0], sx = src_loc[b * 2 + 1];
    const int si = sz - grt;               // 0..3 if owned row
    const int sj = sx - c0;                // 0..3 if owned col
    const bool has_src = ((unsigned)si < 4u) && ((unsigned)sj < 4u);

    // receiver slots: interior owner only (unique writer). pk=(r<<4)|(i<<2)|j
    int rs[RCAP]; int rcnt = 0;
#pragma unroll 1
    for (int r = 0; r < NREC_; ++r) {
        int rz = rec_loc[(b * NREC_ + r) * 2 + 0];
        int rx = rec_loc[(b * NREC_ + r) * 2 + 1];
        int i = rz - grt, j = rx - c0;
        if (rz >= p * IROWS && rz < p * IROWS + IROWS &&
            (unsigned)i < 4u && (unsigned)j < 4u) {
            if (rcnt < RCAP) rs[rcnt] = (r << 4) | (i << 2) | j;
            ++rcnt;
        }
    }
    if (rcnt > RCAP) rcnt = RCAP;
    float* outb = out + (size_t)b * NT_ * NREC_;

    v4f A[4], Bv[4];
    {
        v4f z = {0.f, 0.f, 0.f, 0.f};
#pragma unroll
        for (int i = 0; i < 4; ++i) { A[i] = z; Bv[i] = z; }
    }

    // one step: P <- update(C, P); P becomes current. par = t&1.
    auto step = [&](v4f (&C)[4], v4f (&P)[4], int t, int par) {
        *(v4f*)&pub[par][0][band][c0] = C[0];   // my top row (south halo of band-1)
        *(v4f*)&pub[par][1][band][c0] = C[3];   // my bottom row (north halo of band+1)
        __syncthreads();
        v4f nn, ss;
        if (band > 0)  nn = *(const v4f*)&pub[par][1][band - 1][c0];
        else           { nn.x = 0.f; nn.y = 0.f; nn.z = 0.f; nn.w = 0.f; }
        if (band < 15) ss = *(const v4f*)&pub[par][0][band + 1][c0];
        else           { ss.x = 0.f; ss.y = 0.f; ss.z = 0.f; ss.w = 0.f; }
        const float sv = DT2 * wav[t];
#pragma unroll
        for (int i = 0; i < 4; ++i) {
            v4f n = (i == 0) ? nn : C[i - 1];
            v4f s = (i == 3) ? ss : C[i + 1];
            float wv = dpp_shr1(C[i].w);   // col c0-1 (lane0 -> 0: cf=0 masks)
            float ev = dpp_shl1(C[i].x);   // col c0+4 (lane63 -> 0: cf=0 masks)
            v4f hn;
            { float sm = (n.x + s.x) + (wv     + C[i].y);
              hn.x = fmaf(cf[i].x, fmaf(-4.f, C[i].x, sm), fmaf(2.f, C[i].x, -P[i].x)); }
            { float sm = (n.y + s.y) + (C[i].x + C[i].z);
              hn.y = fmaf(cf[i].y, fmaf(-4.f, C[i].y, sm), fmaf(2.f, C[i].y, -P[i].y)); }
            { float sm = (n.z + s.z) + (C[i].y + C[i].w);
              hn.z = fmaf(cf[i].z, fmaf(-4.f, C[i].z, sm), fmaf(2.f, C[i].z, -P[i].z)); }
            { float sm = (n.w + s.w) + (C[i].z + ev);
              hn.w = fmaf(cf[i].w, fmaf(-4.f, C[i].w, sm), fmaf(2.f, C[i].w, -P[i].w)); }
            if (has_src && si == i) {
                if      (sj == 0) hn.x += sv;
                else if (sj == 1) hn.y += sv;
                else if (sj == 2) hn.z += sv;
                else              hn.w += sv;
            }
            P[i] = hn;
        }
        // receiver gather from the NEW level (registers) -> LDS staging only.
        // Global flush happens once per round; keeps vmcnt==0 across step barriers.
#pragma unroll
        for (int k = 0; k < RCAP; ++k) {
            if (rcnt > k) {
                int pk = rs[k];
                int i = (pk >> 2) & 3, j = pk & 3, r = pk >> 4;
                v4f t01 = (i & 1) ? P[1] : P[0];
                v4f t23 = (i & 1) ? P[3] : P[2];
                v4f rw  = (i & 2) ? t23 : t01;
                float c01 = (j & 1) ? rw.y : rw.x;
                float c23 = (j & 1) ? rw.w : rw.z;
                recbuf[t & (G - 1)][r] = (j & 2) ? c23 : c01;
            }
        }
        // no trailing barrier: next step uses pub[par^1] (parity double-buffer)
    };

    // ghost exchange after round e: A=cur(lvl0), B=prev(lvl1), regs <-> global
    auto exchange = [&](int e) {
        auto gptr = [&](int bk, int side, int lvl, int rr) -> float* {
            return gbuf + (((((size_t)(e & 1) * 64 + bk) * 2 + side) * 2 + lvl)
                           * 16 + rr) * 256;
        };
        if (band >= 4 && band < 12) {      // publish interior halves, both levels
            int side = (band >= 8) ? 1 : 0;
            int rr0 = (band << 2) - (side ? 32 : 16);
#pragma unroll
            for (int i = 0; i < 4; ++i) {
                *(v4f*)&gptr(blk, side, 0, rr0 + i)[c0] = A[i];
                *(v4f*)&gptr(blk, side, 1, rr0 + i)[c0] = Bv[i];
            }
        }
        __syncthreads();                   // every wave's stores vmcnt-drained
        if (tid == 0) {
            __builtin_amdgcn_fence(__ATOMIC_RELEASE, "agent");
            __hip_atomic_store(&flags[blk], e + 1, __ATOMIC_RELEASE,
                               __HIP_MEMORY_SCOPE_AGENT);
            if (p > 0)
                while (__hip_atomic_load(&flags[blk - 1], __ATOMIC_ACQUIRE,
                                         __HIP_MEMORY_SCOPE_AGENT) < e + 1)
                    __builtin_amdgcn_s_sleep(8);
            __builtin_amdgcn_fence(__ATOMIC_ACQUIRE, "agent");
        }
        if (tid == 64 && p < PIECES - 1) { // second wave polls south in parallel
            while (__hip_atomic_load(&flags[blk + 1], __ATOMIC_ACQUIRE,
                                     __HIP_MEMORY_SCOPE_AGENT) < e + 1)
                __builtin_amdgcn_s_sleep(8);
            __builtin_amdgcn_fence(__ATOMIC_ACQUIRE, "agent");
        }
        __syncthreads();                   // all threads ordered after acquire
        if (band < 4 && p > 0) {           // refill top ghost from north neighbor
            int rr0 = band << 2;
#pragma unroll
            for (int i = 0; i < 4; ++i) {
                A[i]  = *(const v4f*)&gptr(blk - 1, 1, 0, rr0 + i)[c0];
                Bv[i] = *(const v4f*)&gptr(blk - 1, 1, 1, rr0 + i)[c0];
            }
        }
        if (band >= 12 && p < PIECES - 1) {  // refill bottom ghost from south
            int rr0 = (band << 2) - 48;
#pragma unroll
            for (int i = 0; i < 4; ++i) {
                A[i]  = *(const v4f*)&gptr(blk + 1, 0, 0, rr0 + i)[c0];
                Bv[i] = *(const v4f*)&gptr(blk + 1, 0, 1, rr0 + i)[c0];
            }
        }
    };

    int t = 0;
#pragma unroll 1
    for (int e = 0; e < ROUNDS; ++e) {
#pragma unroll 1
        for (int s = 0; s < G; s += 2) {
            step(A, Bv, t, 0);      // t even: cur=A, par=0
            step(Bv, A, t + 1, 1);  // t odd:  cur=B, par=1
            t += 2;
        }
        // flush this round's receiver samples: one coalesced masked store.
        // Barrier first: recbuf writes came from scattered owner threads.
        __syncthreads();
        {
            int s = tid >> 6;       // 0..15 = step within round
            int r = tid & 63;       // 0..63 = receiver
            if (recown[r]) outb[(e * G + s) * NREC_ + r] = recbuf[s][r];
        }
        // no barrier needed before next round's recbuf writes: for e<ROUNDS-1
        // the exchange below has two __syncthreads between flush-read and the
        // next round's first recbuf write; last round ends the kernel.
        if (e < ROUNDS - 1) exchange(e);
    }
}

extern "C" void kernel_launch(void* const* d_in, const int* in_sizes, int n_in,
                              void* d_out, int out_size, void* d_ws, size_t ws_size,
                              hipStream_t stream) {
    const float* x   = (const float*)d_in[0];
    const float* vp  = (const float*)d_in[1];
    const int*   src = (const int*)d_in[2];
    const int*   rec = (const int*)d_in[3];
    float*       o   = (float*)d_out;
    int*   flags = (int*)d_ws;
    float* gbuf  = (float*)((char*)d_ws + FLAGS_BYTES);
    (void)hipMemsetAsync(d_ws, 0, FLAGS_BYTES, stream);   // flags must start at 0
    hipLaunchKernelGGL(wave_reg_kernel, dim3(B_ * PIECES), dim3(1024), 0, stream,
                       x, vp, src, rec, o, flags, gbuf);
}